// Round 1
// baseline (214.880 us; speedup 1.0000x reference)
//
#include <hip/hip_runtime.h>
#include <hip/hip_bf16.h>

typedef unsigned short u16;
typedef unsigned int u32;
typedef __attribute__((ext_vector_type(8))) short bf16x8;
typedef __attribute__((ext_vector_type(4))) float f32x4;

#define BATCH 2
#define NSEQ 2048
#define DIM 1024
#define HEADS 16
#define DH 64
#define MTOT (BATCH * NSEQ)   // 4096
#define QKV_N 3072
#define SCALEQ 0.125f

static __device__ __forceinline__ u16 f2bf(float f) {
    union { float f; u32 u; } v; v.f = f;
    u32 r = v.u + 0x7fffu + ((v.u >> 16) & 1u);
    return (u16)(r >> 16);
}

// ---------------- LayerNorm + bf16 cast: x[4096][1024] f32 -> bf16 ----------------
__global__ __launch_bounds__(256) void ln_kernel(const float* __restrict__ x,
                                                 const float* __restrict__ gamma,
                                                 const float* __restrict__ beta,
                                                 u16* __restrict__ out) {
    int row = blockIdx.x;
    int t = threadIdx.x;
    const float4* xr = (const float4*)(x + (size_t)row * DIM);
    float4 v = xr[t];
    float s1 = v.x + v.y + v.z + v.w;
    float s2 = v.x * v.x + v.y * v.y + v.z * v.z + v.w * v.w;
    #pragma unroll
    for (int m = 1; m < 64; m <<= 1) {
        s1 += __shfl_xor(s1, m);
        s2 += __shfl_xor(s2, m);
    }
    __shared__ float r1[4], r2[4];
    int wid = t >> 6, lane = t & 63;
    if (lane == 0) { r1[wid] = s1; r2[wid] = s2; }
    __syncthreads();
    s1 = r1[0] + r1[1] + r1[2] + r1[3];
    s2 = r2[0] + r2[1] + r2[2] + r2[3];
    float mean = s1 * (1.0f / DIM);
    float var = s2 * (1.0f / DIM) - mean * mean;
    float rstd = rsqrtf(var + 1e-5f);
    const float4* gr = (const float4*)gamma;
    const float4* br = (const float4*)beta;
    float4 g = gr[t], b = br[t];
    float o0 = (v.x - mean) * rstd * g.x + b.x;
    float o1 = (v.y - mean) * rstd * g.y + b.y;
    float o2 = (v.z - mean) * rstd * g.z + b.z;
    float o3 = (v.w - mean) * rstd * g.w + b.w;
    ushort4 ov;
    ov.x = f2bf(o0); ov.y = f2bf(o1); ov.z = f2bf(o2); ov.w = f2bf(o3);
    *(ushort4*)(out + (size_t)row * DIM + t * 4) = ov;
}

// ---------------- transpose + cast: in[R][C] f32 -> out[C][R] bf16 ----------------
__global__ __launch_bounds__(256) void transpose_cast_kernel(const float* __restrict__ in,
                                                             u16* __restrict__ out,
                                                             int R, int C) {
    __shared__ float tile[32][33];
    int bx = blockIdx.x;  // C/32
    int by = blockIdx.y;  // R/32
    int t = threadIdx.x;
    int lc = t & 31, lr8 = t >> 5;  // lr8 in [0,8)
    #pragma unroll
    for (int i = 0; i < 4; i++) {
        int rr = lr8 + i * 8;
        tile[rr][lc] = in[(size_t)(by * 32 + rr) * C + bx * 32 + lc];
    }
    __syncthreads();
    #pragma unroll
    for (int i = 0; i < 4; i++) {
        int cc = lr8 + i * 8;
        out[(size_t)(bx * 32 + cc) * R + by * 32 + lc] = f2bf(tile[lc][cc]);
    }
}

// ---------------- GEMM: C[M][N] = A[M][K] * Bt[N][K]^T  (bf16 in, f32 acc) --------
// MODE 0: scatter epilogue -> Q (scaled), K, V  in [b][h][n][d] bf16
// MODE 1: += bias, write f32
template <int MODE>
__global__ __launch_bounds__(256) void gemm_kernel(const u16* __restrict__ A,
                                                   const u16* __restrict__ Bt,
                                                   int M, int N, int K,
                                                   u16* __restrict__ q_out,
                                                   u16* __restrict__ k_out,
                                                   u16* __restrict__ v_out,
                                                   float* __restrict__ out,
                                                   const float* __restrict__ bias) {
    const int BK = 64, LDT = BK + 8;  // pad 8 bf16 = 16B keeps 16B alignment, kills conflicts
    __shared__ u16 As[128 * LDT];
    __shared__ u16 Bs[128 * LDT];
    int bm = blockIdx.y, bn = blockIdx.x;
    int t = threadIdx.x;
    int wid = t >> 6, lane = t & 63;
    int l15 = lane & 15, l4 = lane >> 4;
    int wm = (wid >> 1) * 64, wn = (wid & 1) * 64;

    f32x4 acc[4][4] = {};

    const u16* Abase = A + (size_t)(bm * 128) * K;
    const u16* Bbase = Bt + (size_t)(bn * 128) * K;
    int srow = t >> 3;            // 0..31
    int scol = (t & 7) * 8;       // 0..56

    for (int k0 = 0; k0 < K; k0 += BK) {
        __syncthreads();
        #pragma unroll
        for (int i = 0; i < 4; i++) {
            int r = srow + i * 32;
            int4 av = *(const int4*)(Abase + (size_t)r * K + k0 + scol);
            *(int4*)(&As[r * LDT + scol]) = av;
            int4 bv = *(const int4*)(Bbase + (size_t)r * K + k0 + scol);
            *(int4*)(&Bs[r * LDT + scol]) = bv;
        }
        __syncthreads();
        #pragma unroll
        for (int kk = 0; kk < BK; kk += 32) {
            bf16x8 af[4], bf[4];
            #pragma unroll
            for (int i = 0; i < 4; i++) {
                af[i] = *(const bf16x8*)(&As[(wm + i * 16 + l15) * LDT + kk + l4 * 8]);
                bf[i] = *(const bf16x8*)(&Bs[(wn + i * 16 + l15) * LDT + kk + l4 * 8]);
            }
            #pragma unroll
            for (int i = 0; i < 4; i++)
                #pragma unroll
                for (int j = 0; j < 4; j++)
                    acc[i][j] = __builtin_amdgcn_mfma_f32_16x16x32_bf16(af[i], bf[j], acc[i][j], 0, 0, 0);
        }
    }

    #pragma unroll
    for (int i = 0; i < 4; i++) {
        #pragma unroll
        for (int j = 0; j < 4; j++) {
            #pragma unroll
            for (int r = 0; r < 4; r++) {
                int grow = bm * 128 + wm + i * 16 + l4 * 4 + r;
                int gcol = bn * 128 + wn + j * 16 + l15;
                float val = acc[i][j][r];
                if (MODE == 0) {
                    int part = gcol >> 10;
                    int inner = gcol & 1023;
                    int h = inner >> 6, d = inner & 63;
                    int b = grow >> 11, n = grow & 2047;
                    size_t off = (((size_t)(b * HEADS + h)) * NSEQ + n) * DH + d;
                    if (part == 0) q_out[off] = f2bf(val * SCALEQ);
                    else if (part == 1) k_out[off] = f2bf(val);
                    else v_out[off] = f2bf(val);
                } else {
                    out[(size_t)grow * N + gcol] = val + bias[gcol];
                }
            }
        }
    }
}

// ---------------- flash attention: per (b,h), Q-tile 128 rows, KV tiles of 64 -----
__global__ __launch_bounds__(256) void attn_kernel(const u16* __restrict__ Q,
                                                   const u16* __restrict__ Kb,
                                                   const u16* __restrict__ Vb,
                                                   u16* __restrict__ out) {
    const int KVB = 64, LDK = 72;
    __shared__ u16 Ks[64 * LDK];      // [kv][d] (+pad)
    __shared__ u16 Vs[64 * LDK];      // transposed: [d][kv] (+pad)
    __shared__ u16 Ps[4 * 32 * LDK];  // per-wave P: [32 q rows][64 kv] (+pad)

    int bh = blockIdx.x;   // 0..31  (b*16+h)
    int qt = blockIdx.y;   // 0..15
    const u16* Qh = Q + (size_t)bh * NSEQ * DH;
    const u16* Kh = Kb + (size_t)bh * NSEQ * DH;
    const u16* Vh = Vb + (size_t)bh * NSEQ * DH;

    int t = threadIdx.x, wid = t >> 6, lane = t & 63;
    int l15 = lane & 15, l4 = lane >> 4;
    int qbase = qt * 128 + wid * 32;

    // Q fragments: wave's 32 rows, k = 0..63 (2 k-steps)
    bf16x8 qf[2][2];
    #pragma unroll
    for (int mi = 0; mi < 2; mi++)
        #pragma unroll
        for (int kk = 0; kk < 2; kk++)
            qf[mi][kk] = *(const bf16x8*)(Qh + (size_t)(qbase + mi * 16 + l15) * DH + kk * 32 + l4 * 8);

    f32x4 o[2][4] = {};
    float mrun[2][4], ell[2][4];
    #pragma unroll
    for (int mi = 0; mi < 2; mi++)
        #pragma unroll
        for (int r = 0; r < 4; r++) { mrun[mi][r] = -1e30f; ell[mi][r] = 0.f; }

    int srow = t >> 2;          // 0..63
    int scolv = (t & 3) * 16;   // 0,16,32,48

    for (int kt = 0; kt < NSEQ; kt += KVB) {
        __syncthreads();
        // stage K [kv][d] and V transposed [d][kv]
        {
            const u16* krow = Kh + (size_t)(kt + srow) * DH + scolv;
            int4 k0 = *(const int4*)(krow);
            int4 k1 = *(const int4*)(krow + 8);
            *(int4*)(&Ks[srow * LDK + scolv]) = k0;
            *(int4*)(&Ks[srow * LDK + scolv + 8]) = k1;
            const u16* vrow = Vh + (size_t)(kt + srow) * DH + scolv;
            int4 v0 = *(const int4*)(vrow);
            int4 v1 = *(const int4*)(vrow + 8);
            union { int4 q; u16 s[8]; } uv0, uv1;
            uv0.q = v0; uv1.q = v1;
            #pragma unroll
            for (int i = 0; i < 8; i++) Vs[(scolv + i) * LDK + srow] = uv0.s[i];
            #pragma unroll
            for (int i = 0; i < 8; i++) Vs[(scolv + 8 + i) * LDK + srow] = uv1.s[i];
        }
        __syncthreads();

        // S = Q K^T   (per wave: 32 q rows x 64 kv cols)
        f32x4 s[2][4] = {};
        #pragma unroll
        for (int kk = 0; kk < 2; kk++) {
            bf16x8 kf[4];
            #pragma unroll
            for (int nj = 0; nj < 4; nj++)
                kf[nj] = *(const bf16x8*)(&Ks[(nj * 16 + l15) * LDK + kk * 32 + l4 * 8]);
            #pragma unroll
            for (int mi = 0; mi < 2; mi++)
                #pragma unroll
                for (int nj = 0; nj < 4; nj++)
                    s[mi][nj] = __builtin_amdgcn_mfma_f32_16x16x32_bf16(qf[mi][kk], kf[nj], s[mi][nj], 0, 0, 0);
        }

        // online softmax; write P (bf16) to per-wave LDS region
        #pragma unroll
        for (int mi = 0; mi < 2; mi++) {
            #pragma unroll
            for (int r = 0; r < 4; r++) {
                float tm = s[mi][0][r];
                #pragma unroll
                for (int nj = 1; nj < 4; nj++) tm = fmaxf(tm, s[mi][nj][r]);
                #pragma unroll
                for (int mk = 1; mk < 16; mk <<= 1) tm = fmaxf(tm, __shfl_xor(tm, mk));
                float mold = mrun[mi][r];
                float mnew = fmaxf(mold, tm);
                float sc = __expf(mold - mnew);
                float rs = 0.f;
                int prow = (wid * 32 + mi * 16 + l4 * 4 + r) * LDK;
                #pragma unroll
                for (int nj = 0; nj < 4; nj++) {
                    float p = __expf(s[mi][nj][r] - mnew);
                    rs += p;
                    Ps[prow + nj * 16 + l15] = f2bf(p);
                }
                #pragma unroll
                for (int mk = 1; mk < 16; mk <<= 1) rs += __shfl_xor(rs, mk);
                ell[mi][r] = ell[mi][r] * sc + rs;
                mrun[mi][r] = mnew;
                #pragma unroll
                for (int di = 0; di < 4; di++) o[mi][di][r] *= sc;
            }
        }
        asm volatile("s_waitcnt lgkmcnt(0)" ::: "memory");

        // O += P V   (A = P [q][kv], B = V [kv][d] read from transposed Vs)
        #pragma unroll
        for (int ks = 0; ks < 2; ks++) {
            bf16x8 pf[2], vf[4];
            #pragma unroll
            for (int mi = 0; mi < 2; mi++)
                pf[mi] = *(const bf16x8*)(&Ps[(wid * 32 + mi * 16 + l15) * LDK + ks * 32 + l4 * 8]);
            #pragma unroll
            for (int di = 0; di < 4; di++)
                vf[di] = *(const bf16x8*)(&Vs[(di * 16 + l15) * LDK + ks * 32 + l4 * 8]);
            #pragma unroll
            for (int mi = 0; mi < 2; mi++)
                #pragma unroll
                for (int di = 0; di < 4; di++)
                    o[mi][di] = __builtin_amdgcn_mfma_f32_16x16x32_bf16(pf[mi], vf[di], o[mi][di], 0, 0, 0);
        }
    }

    // epilogue: out[b*2048+n][h*64+d] bf16
    int b = bh >> 4, h = bh & 15;
    #pragma unroll
    for (int mi = 0; mi < 2; mi++) {
        #pragma unroll
        for (int di = 0; di < 4; di++) {
            #pragma unroll
            for (int r = 0; r < 4; r++) {
                int n = qbase + mi * 16 + l4 * 4 + r;
                int col = h * DH + di * 16 + l15;
                float val = o[mi][di][r] / ell[mi][r];
                out[(size_t)(b * NSEQ + n) * DIM + col] = f2bf(val);
            }
        }
    }
}

extern "C" void kernel_launch(void* const* d_in, const int* in_sizes, int n_in,
                              void* d_out, int out_size, void* d_ws, size_t ws_size,
                              hipStream_t stream) {
    const float* x     = (const float*)d_in[0];
    const float* gamma = (const float*)d_in[1];
    const float* beta  = (const float*)d_in[2];
    const float* w_qkv = (const float*)d_in[3];
    const float* w_out = (const float*)d_in[4];
    const float* b_out = (const float*)d_in[5];
    float* out = (float*)d_out;

    char* ws = (char*)d_ws;
    u16* x_ln  = (u16*)ws; ws += (size_t)MTOT * DIM * 2;        // 8 MB
    u16* wqkvT = (u16*)ws; ws += (size_t)QKV_N * DIM * 2;       // 6 MB
    u16* woutT = (u16*)ws; ws += (size_t)DIM * DIM * 2;         // 2 MB
    u16* Qb    = (u16*)ws; ws += (size_t)BATCH * HEADS * NSEQ * DH * 2;  // 8 MB
    u16* Kb    = (u16*)ws; ws += (size_t)BATCH * HEADS * NSEQ * DH * 2;  // 8 MB
    u16* Vb    = (u16*)ws; ws += (size_t)BATCH * HEADS * NSEQ * DH * 2;  // 8 MB
    u16* attn  = (u16*)ws; ws += (size_t)MTOT * DIM * 2;        // 8 MB

    ln_kernel<<<MTOT, 256, 0, stream>>>(x, gamma, beta, x_ln);
    transpose_cast_kernel<<<dim3(QKV_N / 32, DIM / 32), 256, 0, stream>>>(w_qkv, wqkvT, DIM, QKV_N);
    transpose_cast_kernel<<<dim3(DIM / 32, DIM / 32), 256, 0, stream>>>(w_out, woutT, DIM, DIM);

    gemm_kernel<0><<<dim3(QKV_N / 128, MTOT / 128), 256, 0, stream>>>(
        x_ln, wqkvT, MTOT, QKV_N, DIM, Qb, Kb, Vb, nullptr, nullptr);

    attn_kernel<<<dim3(BATCH * HEADS, NSEQ / 128), 256, 0, stream>>>(Qb, Kb, Vb, attn);

    gemm_kernel<1><<<dim3(DIM / 128, MTOT / 128), 256, 0, stream>>>(
        attn, woutT, MTOT, DIM, DIM, nullptr, nullptr, nullptr, out, b_out);
}